// Round 10
// baseline (523.185 us; speedup 1.0000x reference)
//
#include <hip/hip_runtime.h>
#include <hip/hip_bf16.h>
#include <math.h>

#define BB 2
#define NN 2048
#define DD 512
#define HH 8
#define LL 2
#define TT (BB*NN)   // 4096 tokens

typedef short short8 __attribute__((ext_vector_type(8)));
typedef float floatx4 __attribute__((ext_vector_type(4)));

__device__ __forceinline__ unsigned short f2b(float v) {
    union { float f; unsigned u; } x; x.f = v;
    unsigned r = x.u + 0x7fff + ((x.u >> 16) & 1);   // RNE
    return (unsigned short)(r >> 16);
}

__device__ __forceinline__ float b2f(unsigned short b) {
    union { unsigned u; float f; } x; x.u = ((unsigned)b) << 16; return x.f;
}

__device__ __forceinline__ unsigned fbits(float v) {
    union { float f; unsigned u; } x; x.f = v; return x.u;
}

// pack two fp32 -> two bf16 (RTZ), little-endian [lo=a, hi=b]
__device__ __forceinline__ unsigned pk_bf16_rtz(float a, float b) {
#if __has_builtin(__builtin_amdgcn_perm)
    return __builtin_amdgcn_perm(fbits(b), fbits(a), 0x07060302);
#else
    return (fbits(b) & 0xFFFF0000u) | (fbits(a) >> 16);
#endif
}

// atomic add of a bf16 pair at 4B-aligned address (HW packed atomic; CAS fallback)
__device__ __forceinline__ void atomic_pk_add_bf16(unsigned short* p, float lo, float hi) {
#if __has_builtin(__builtin_amdgcn_global_atomic_fadd_v2bf16)
    typedef short s2 __attribute__((ext_vector_type(2)));
    s2 v;
    v[0] = (short)f2b(lo);
    v[1] = (short)f2b(hi);
    __builtin_amdgcn_global_atomic_fadd_v2bf16((__attribute__((address_space(1))) s2*)p, v);
#else
    unsigned* a = (unsigned*)p;
    unsigned old = *a, assumed;
    do {
        assumed = old;
        float nlo = b2f((unsigned short)(assumed & 0xffff)) + lo;
        float nhi = b2f((unsigned short)(assumed >> 16)) + hi;
        unsigned nv = ((unsigned)f2b(nhi) << 16) | (unsigned)f2b(nlo);
        old = atomicCAS(a, assumed, nv);
    } while (old != assumed);
#endif
}

// ---------------- dst = src + bias (row-broadcast); src may alias dst ----------------
__global__ __launch_bounds__(256) void k_bias_add(const float* __restrict__ src,
                                                  const float* __restrict__ bias,
                                                  float* __restrict__ dst) {
    int i = blockIdx.x * 256 + threadIdx.x;
    dst[i] = src[i] + bias[i & (DD - 1)];
}

// ---------------- layernorm (opt. fused embed): x = LN(src)*g + b (bf16) ----------------
// EMB: src = emb + pos (also written to hout for the residual stream); else src = hin.
template <int EMB>
__global__ __launch_bounds__(256) void k_ln(const float* __restrict__ hin,
                                            unsigned short* __restrict__ xout,
                                            const float* __restrict__ g,
                                            const float* __restrict__ b,
                                            const float* __restrict__ emb,
                                            const float* __restrict__ pos,
                                            float* __restrict__ hout) {
    __shared__ float red[4];
    __shared__ float bc1, bc2;
    int t = blockIdx.x;
    int tid = threadIdx.x;
    int lane = tid & 63, wv = tid >> 6;
    float v0, v1;
    if (EMB) {
        const float* erow = emb + (size_t)t * DD;
        const float* prow = pos + (size_t)(t & (NN - 1)) * DD;
        v0 = erow[tid] + prow[tid];
        v1 = erow[tid + 256] + prow[tid + 256];
        hout[(size_t)t * DD + tid] = v0;
        hout[(size_t)t * DD + tid + 256] = v1;
    } else {
        const float* row = hin + (size_t)t * DD;
        v0 = row[tid];
        v1 = row[tid + 256];
    }

    float s = v0 + v1;
#pragma unroll
    for (int o = 32; o; o >>= 1) s += __shfl_down(s, o, 64);
    if (lane == 0) red[wv] = s;
    __syncthreads();
    if (tid == 0) bc1 = (red[0] + red[1] + red[2] + red[3]) * (1.0f / DD);
    __syncthreads();
    float mu = bc1;
    float d0 = v0 - mu, d1 = v1 - mu;
    s = d0 * d0 + d1 * d1;
#pragma unroll
    for (int o = 32; o; o >>= 1) s += __shfl_down(s, o, 64);
    if (lane == 0) red[wv] = s;
    __syncthreads();
    if (tid == 0) bc2 = (red[0] + red[1] + red[2] + red[3]) * (1.0f / DD);
    __syncthreads();
    float rstd = rsqrtf(bc2 + 1e-5f);
    xout[(size_t)t * DD + tid]       = f2b(d0 * rstd * g[tid] + b[tid]);
    xout[(size_t)t * DD + tid + 256] = f2b(d1 * rstd * g[tid + 256] + b[tid + 256]);
}

__device__ __forceinline__ float gelu_new(float v) {
    const float c = 0.7978845608028654f;   // sqrt(2/pi)
    float u = c * (v + 0.044715f * v * v * v);
    return 0.5f * v * (1.0f + tanhf(u));
}

// ---------------- all-weight transpose+convert, both layers, one dispatch ----------------
#define PL 3145728   // per-layer bf16 WT region (elements)
__global__ __launch_bounds__(256) void k_wt_all(const float* __restrict__ c_attn_w,
                                                const float* __restrict__ out_w,
                                                const float* __restrict__ c_fc_w,
                                                const float* __restrict__ c_proj_w,
                                                unsigned short* __restrict__ wbuf) {
    __shared__ unsigned short t[64][72];
    int bx = blockIdx.x;
    int l = bx / 768;
    int r = bx - l * 768;
    const float* W; unsigned short* WT; int K, N;
    if (r < 192)      { W = c_attn_w + (size_t)l * 512 * 1536; WT = wbuf + (size_t)l * PL;           K = 512;  N = 1536; }
    else if (r < 256) { r -= 192; W = out_w  + (size_t)l * 512 * 512;  WT = wbuf + (size_t)l * PL + 786432;  K = 512;  N = 512; }
    else if (r < 512) { r -= 256; W = c_fc_w + (size_t)l * 512 * 2048; WT = wbuf + (size_t)l * PL + 1048576; K = 512;  N = 2048; }
    else              { r -= 512; W = c_proj_w + (size_t)l * 2048 * 512; WT = wbuf + (size_t)l * PL + 2097152; K = 2048; N = 512; }
    int tiles_n = N >> 6;
    int n0 = (r % tiles_n) * 64, k0 = (r / tiles_n) * 64;

    int tid = threadIdx.x;
    int rr = tid >> 2;
    int c0 = (tid & 3) * 16;
    const float* src = W + (size_t)(k0 + rr) * N + n0 + c0;
#pragma unroll
    for (int u = 0; u < 4; u++) {
        float4 v = *(const float4*)&src[u * 4];
        t[c0 + u * 4 + 0][rr] = f2b(v.x);
        t[c0 + u * 4 + 1][rr] = f2b(v.y);
        t[c0 + u * 4 + 2][rr] = f2b(v.z);
        t[c0 + u * 4 + 3][rr] = f2b(v.w);
    }
    __syncthreads();
    unsigned short* dst = WT + (size_t)(n0 + rr) * K + k0 + c0;
#pragma unroll
    for (int u = 0; u < 4; u++)
        *(uint2*)&dst[u * 4] = *(const uint2*)&t[rr][c0 + u * 4];
}

// ---------------- MFMA GEMM: 128x128, reg-prefetch + LDS dbuf, ONE barrier/iter -----------
// C[M x N] (+)= A[M x K](bf16) @ Bt[N x K]^T. 4 waves (2x2), each 4x4 frags of 16x16x32.
// ATOMIC=1: fp32 atomicAdd epilogue (+bias when z==0). ATOMIC=2: packed-bf16 atomic
// epilogue into Cb (pairs formed via shfl_xor(1), even lanes issue).
template <int ACT, int BF16OUT, int ATOMIC>
__global__ __launch_bounds__(256) void k_mgemm(const unsigned short* __restrict__ Ab,
                                               const unsigned short* __restrict__ Bt,
                                               const float* __restrict__ bias,
                                               float* __restrict__ Cp,
                                               unsigned short* __restrict__ Cb,
                                               int Kfull, int Kchunk, int N) {
    __shared__ unsigned short Als[2][8 * 512];   // frag-contiguous: 8 blocks of 16 rows x 32 k
    __shared__ unsigned short Bls[2][8 * 512];

    int tid = threadIdx.x;
    int l = tid & 63, w = tid >> 6;
    int wm = w >> 1, wn = w & 1;
    int m0 = blockIdx.y * 128, n0 = blockIdx.x * 128;
    int kb = blockIdx.z * Kchunk;
    int lr = l & 15;
    int lk = (l >> 4) * 8;

    const unsigned short* Ap0 = Ab + (size_t)(m0 + (w * 2 + 0) * 16 + lr) * Kfull + kb + lk;
    const unsigned short* Ap1 = Ab + (size_t)(m0 + (w * 2 + 1) * 16 + lr) * Kfull + kb + lk;
    const unsigned short* Bp0 = Bt + (size_t)(n0 + (w * 2 + 0) * 16 + lr) * Kfull + kb + lk;
    const unsigned short* Bp1 = Bt + (size_t)(n0 + (w * 2 + 1) * 16 + lr) * Kfull + kb + lk;
    int la0 = (w * 2 + 0) * 512 + l * 8;
    int la1 = (w * 2 + 1) * 512 + l * 8;

    floatx4 acc[4][4];
#pragma unroll
    for (int i = 0; i < 4; i++)
#pragma unroll
        for (int j = 0; j < 4; j++) acc[i][j] = (floatx4){0.f, 0.f, 0.f, 0.f};

    int nit = Kchunk >> 5;

    // prologue: tile 0 -> buf0; prefetch tile 1 -> regs
    uint4 ra0 = *(const uint4*)Ap0;
    uint4 ra1 = *(const uint4*)Ap1;
    uint4 rb0 = *(const uint4*)Bp0;
    uint4 rb1 = *(const uint4*)Bp1;
    *(uint4*)&Als[0][la0] = ra0;
    *(uint4*)&Als[0][la1] = ra1;
    *(uint4*)&Bls[0][la0] = rb0;
    *(uint4*)&Bls[0][la1] = rb1;
    if (nit > 1) {
        ra0 = *(const uint4*)(Ap0 + 32);
        ra1 = *(const uint4*)(Ap1 + 32);
        rb0 = *(const uint4*)(Bp0 + 32);
        rb1 = *(const uint4*)(Bp1 + 32);
    }
    __syncthreads();

    for (int it = 0; it < nit; it++) {
        int c = it & 1;
        if (it + 1 < nit) {          // regs hold tile it+1 -> other buffer
            *(uint4*)&Als[c ^ 1][la0] = ra0;
            *(uint4*)&Als[c ^ 1][la1] = ra1;
            *(uint4*)&Bls[c ^ 1][la0] = rb0;
            *(uint4*)&Bls[c ^ 1][la1] = rb1;
        }
        if (it + 2 < nit) {          // prefetch tile it+2
            int ko = (it + 2) << 5;
            ra0 = *(const uint4*)(Ap0 + ko);
            ra1 = *(const uint4*)(Ap1 + ko);
            rb0 = *(const uint4*)(Bp0 + ko);
            rb1 = *(const uint4*)(Bp1 + ko);
        }
        short8 a[4], b[4];
#pragma unroll
        for (int i = 0; i < 4; i++) {
            a[i] = *(const short8*)&Als[c][(wm * 4 + i) * 512 + l * 8];
            b[i] = *(const short8*)&Bls[c][(wn * 4 + i) * 512 + l * 8];
        }
#pragma unroll
        for (int i = 0; i < 4; i++)
#pragma unroll
            for (int j = 0; j < 4; j++)
                acc[i][j] = __builtin_amdgcn_mfma_f32_16x16x32_bf16(a[i], b[j], acc[i][j], 0, 0, 0);
        __syncthreads();
    }

    // epilogue: C/D layout col=lane&15, row=(lane>>4)*4+reg
    int col_in = l & 15, rquad = (l >> 4) * 4;
    bool addb = (ATOMIC == 0) || (bias != nullptr && blockIdx.z == 0);
#pragma unroll
    for (int i = 0; i < 4; i++) {
        int gm_base = m0 + wm * 64 + i * 16 + rquad;
#pragma unroll
        for (int j = 0; j < 4; j++) {
            int gn = n0 + wn * 64 + j * 16 + col_in;
            float bv = addb ? bias[gn] : 0.0f;
#pragma unroll
            for (int r = 0; r < 4; r++) {
                size_t off = (size_t)(gm_base + r) * N + gn;
                if (ATOMIC == 1) {
                    atomicAdd(&Cp[off], acc[i][j][r] + bv);
                } else if (ATOMIC == 2) {
                    float v = acc[i][j][r] + bv;
                    float pv = __shfl_xor(v, 1);   // partner column (gn^1)
                    if ((l & 1) == 0)
                        atomic_pk_add_bf16(&Cb[off], v, pv);
                } else {
                    float v = acc[i][j][r] + bv;
                    if (ACT) v = gelu_new(v);
                    if (BF16OUT) Cb[off] = f2b(v);
                    else Cp[off] = v;
                }
            }
        }
    }
}

// ---------------- MFMA flash attention: 2-barrier single-buffer (R7 structure) ------------
// + R9 VALU path: p = 2^(s*C1+C2), RTZ perm-pack, ones-vector MFMA row sums.
// qkv bf16 [T,1536] (q|k|v). S^T = K·Q^T (A=K, B=Q); p=0 exactly on the diagonal.
__global__ __launch_bounds__(256) void k_attn_mfma(const unsigned short* __restrict__ qkv,
                                                   unsigned short* __restrict__ xatt) {
    __shared__ unsigned short Ks[64 * 72];    // K tile [key][d]
    __shared__ unsigned short Vt[64 * 72];    // V^T tile [d][key]
    __shared__ unsigned short Pls[64 * 72];   // P tile [m][key] (wave-private rows)

    int qt = blockIdx.x, hd = blockIdx.y, b = blockIdx.z;
    int tid = threadIdx.x;
    int l = tid & 63, w = tid >> 6;
    int lr = l & 15, quad = l >> 4;

    const size_t base = (size_t)b * NN * 1536;

    // Q frags (B-operand): lane col m=lr, k=d=quad*8+j (+32*ss)
    short8 qf[2];
    {
        const unsigned short* qrow = qkv + base + (size_t)(qt * 64 + w * 16 + lr) * 1536 + hd * 64;
        qf[0] = *(const short8*)&qrow[quad * 8];
        qf[1] = *(const short8*)&qrow[quad * 8 + 32];
    }
    short8 onef;
#pragma unroll
    for (int i = 0; i < 8; i++) onef[i] = (short)0x3F80;   // bf16 1.0

    floatx4 O[4];       // O[m=quad*4+reg][d=jd*16+lr]
#pragma unroll
    for (int jd = 0; jd < 4; jd++) O[jd] = (floatx4){0.f, 0.f, 0.f, 0.f};
    floatx4 sacc = (floatx4){0.f, 0.f, 0.f, 0.f};   // P row sums (all cols identical)

    // staging maps
    int sr = tid >> 2, sc = (tid & 3) * 16;          // K: row sr (key), 16-d chunk sc
    int vk = (tid & 15) * 4, vd = (tid >> 4) * 4;    // V: 4 keys x 4 d per thread
    const unsigned short* Kbase = qkv + base + 512 + hd * 64;
    const unsigned short* Vbase = qkv + base + 1024 + hd * 64;

    uint4 rk0, rk1;
    union { uint2 u; unsigned short s[4]; } rv[4];
    // prefetch kt=0
    rk0 = *(const uint4*)&Kbase[(size_t)sr * 1536 + sc];
    rk1 = *(const uint4*)&Kbase[(size_t)sr * 1536 + sc + 8];
#pragma unroll
    for (int i = 0; i < 4; i++)
        rv[i].u = *(const uint2*)&Vbase[(size_t)(vk + i) * 1536 + vd];

    const float C1 = 0.18033688f;     // 0.125*log2(e)
    const float C2 = -11.5415603f;    // -8*log2(e)
    int mq = w * 16 + lr;             // this lane's query row within the 64-row tile

    for (int kt = 0; kt < 32; kt++) {
        __syncthreads();   // prev iter's Ks/Vt reads done
        *(uint4*)&Ks[sr * 72 + sc]     = rk0;
        *(uint4*)&Ks[sr * 72 + sc + 8] = rk1;
#pragma unroll
        for (int j = 0; j < 4; j++) {
            union { uint2 u; unsigned short s[4]; } pk;
            pk.s[0] = rv[0].s[j]; pk.s[1] = rv[1].s[j];
            pk.s[2] = rv[2].s[j]; pk.s[3] = rv[3].s[j];
            *(uint2*)&Vt[(vd + j) * 72 + vk] = pk.u;
        }
        __syncthreads();
        if (kt < 31) {   // prefetch next K/V tile
            int kn = (kt + 1) * 64;
            rk0 = *(const uint4*)&Kbase[(size_t)(kn + sr) * 1536 + sc];
            rk1 = *(const uint4*)&Kbase[(size_t)(kn + sr) * 1536 + sc + 8];
#pragma unroll
            for (int i = 0; i < 4; i++)
                rv[i].u = *(const uint2*)&Vbase[(size_t)(kn + vk + i) * 1536 + vd];
        }

        // S^T = K Q^T: s[jn] rows key=jn*16+quad*4+reg, col m=lr
        floatx4 s[4];
#pragma unroll
        for (int jn = 0; jn < 4; jn++) s[jn] = (floatx4){0.f, 0.f, 0.f, 0.f};
#pragma unroll
        for (int ss = 0; ss < 2; ss++)
#pragma unroll
            for (int jn = 0; jn < 4; jn++) {
                short8 ak = *(const short8*)&Ks[(jn * 16 + lr) * 72 + ss * 32 + quad * 8];
                s[jn] = __builtin_amdgcn_mfma_f32_16x16x32_bf16(ak, qf[ss], s[jn], 0, 0, 0);
            }

        // p = 2^(s*C1 + C2); diag p=0; RTZ-pack 4 consecutive keys -> b64 write
#pragma unroll
        for (int jn = 0; jn < 4; jn++) {
            float p[4];
#pragma unroll
            for (int r = 0; r < 4; r++) {
                p[r] = exp2f(fmaf(s[jn][r], C1, C2));
                if (kt == qt && mq == jn * 16 + quad * 4 + r) p[r] = 0.0f;
            }
            uint2 pk;
            pk.x = pk_bf16_rtz(p[0], p[1]);
            pk.y = pk_bf16_rtz(p[2], p[3]);
            *(uint2*)&Pls[mq * 72 + jn * 16 + quad * 4] = pk;
        }

        // O += P V ; sacc += P 1  (P rows written/read by the same wave; no barrier needed)
#pragma unroll
        for (int ss = 0; ss < 2; ss++) {
            short8 ap = *(const short8*)&Pls[(w * 16 + lr) * 72 + ss * 32 + quad * 8];
#pragma unroll
            for (int jd = 0; jd < 4; jd++) {
                short8 bv = *(const short8*)&Vt[(jd * 16 + lr) * 72 + ss * 32 + quad * 8];
                O[jd] = __builtin_amdgcn_mfma_f32_16x16x32_bf16(ap, bv, O[jd], 0, 0, 0);
            }
            sacc = __builtin_amdgcn_mfma_f32_16x16x32_bf16(ap, onef, sacc, 0, 0, 0);
        }
    }

    // normalize + store (sacc[r] = row sum for token quad*4+r)
#pragma unroll
    for (int r = 0; r < 4; r++) {
        float inv = 1.0f / sacc[r];
        size_t tok = (size_t)b * NN + qt * 64 + w * 16 + quad * 4 + r;
#pragma unroll
        for (int jd = 0; jd < 4; jd++)
            xatt[tok * DD + hd * 64 + jd * 16 + lr] = f2b(O[jd][r] * inv);
    }
}

extern "C" void kernel_launch(void* const* d_in, const int* in_sizes, int n_in,
                              void* d_out, int out_size, void* d_ws, size_t ws_size,
                              hipStream_t stream) {
    const float* emb      = (const float*)d_in[0];
    const float* pos      = (const float*)d_in[1];
    const float* c_attn_w = (const float*)d_in[2];
    const float* c_attn_b = (const float*)d_in[3];
    const float* out_w    = (const float*)d_in[4];
    const float* out_b    = (const float*)d_in[5];
    const float* ln1_g    = (const float*)d_in[6];
    const float* ln1_b    = (const float*)d_in[7];
    const float* c_fc_w   = (const float*)d_in[8];
    const float* c_fc_b   = (const float*)d_in[9];
    const float* c_proj_w = (const float*)d_in[10];
    const float* c_proj_b = (const float*)d_in[11];
    const float* ln2_g    = (const float*)d_in[12];
    const float* ln2_b    = (const float*)d_in[13];

    // workspace: 8 + 16.8 + 4 + 4 + 12.6 = ~45.4 MB
    char* p = (char*)d_ws;
    float* h = (float*)p;                       p += (size_t)TT * DD * 4;      // fp32 residual
    unsigned short* act = (unsigned short*)p;   p += (size_t)TT * 2048 * 2;    // qkvb/ffa union
    unsigned short* x = (unsigned short*)p;     p += (size_t)TT * DD * 2;      // LN out
    unsigned short* xatt = (unsigned short*)p;  p += (size_t)TT * DD * 2;      // attn out
    unsigned short* wbuf = (unsigned short*)p;                                 // bf16 W^T (both layers)

    unsigned short* qkvb = act;
    unsigned short* ffa  = act;
    float* out = (float*)d_out;

    k_wt_all<<<1536, 256, 0, stream>>>(c_attn_w, out_w, c_fc_w, c_proj_w, wbuf);

    for (int l = 0; l < LL; l++) {
        unsigned short* wqkv_t  = wbuf + (size_t)l * PL;
        unsigned short* wout_t  = wqkv_t + 786432;
        unsigned short* wfc_t   = wqkv_t + 1048576;
        unsigned short* wproj_t = wqkv_t + 2097152;

        // x = LN1(h)  (layer 0: fused embed, also writes h)
        if (l == 0)
            k_ln<1><<<TT, 256, 0, stream>>>(nullptr, x, ln1_g, ln1_b, emb, pos, h);
        else
            k_ln<0><<<TT, 256, 0, stream>>>(h, x, ln1_g + l * DD, ln1_b + l * DD,
                                            nullptr, nullptr, nullptr);
        // qkvb = x @ Wqkv + b  (split-K=2, packed-bf16 atomics; zero-init first)
        hipMemsetAsync(qkvb, 0, (size_t)TT * 1536 * 2, stream);
        k_mgemm<0, 0, 2><<<dim3(1536 / 128, TT / 128, 2), 256, 0, stream>>>(
            x, wqkv_t, c_attn_b + l * 1536, nullptr, qkvb, 512, 256, 1536);
        // xatt = attention(qkvb)  (bf16)
        k_attn_mfma<<<dim3(NN / 64, HH, BB), 256, 0, stream>>>(qkvb, xatt);
        // h += xatt @ Wout + out_b  (split-K=2 fp32 atomics; bias folded into z==0)
        k_mgemm<0, 0, 1><<<dim3(512 / 128, TT / 128, 2), 256, 0, stream>>>(
            xatt, wout_t, out_b + l * DD, h, nullptr, 512, 256, 512);
        // x = LN2(h)
        k_ln<0><<<TT, 256, 0, stream>>>(h, x, ln2_g + l * DD, ln2_b + l * DD,
                                        nullptr, nullptr, nullptr);
        // ffa = gelu(x @ Wfc + b)  (bf16; qkvb dead)
        k_mgemm<1, 1, 0><<<dim3(2048 / 128, TT / 128), 256, 0, stream>>>(
            x, wfc_t, c_fc_b + l * 2048, nullptr, ffa, 512, 512, 2048);
        // h/out += ffa @ Wproj + proj_b  (split-K=4 fp32 atomics)
        if (l == LL - 1) {
            k_bias_add<<<TT * DD / 256, 256, 0, stream>>>(h, c_proj_b + l * DD, out);
            k_mgemm<0, 0, 1><<<dim3(512 / 128, TT / 128, 4), 256, 0, stream>>>(
                ffa, wproj_t, nullptr, out, nullptr, 2048, 512, 512);
        } else {
            k_mgemm<0, 0, 1><<<dim3(512 / 128, TT / 128, 4), 256, 0, stream>>>(
                ffa, wproj_t, c_proj_b + l * DD, h, nullptr, 2048, 512, 512);
        }
    }
}

// Round 11
// 432.460 us; speedup vs baseline: 1.2098x; 1.2098x over previous
//
#include <hip/hip_runtime.h>
#include <hip/hip_bf16.h>
#include <math.h>

#define BB 2
#define NN 2048
#define DD 512
#define HH 8
#define LL 2
#define TT (BB*NN)   // 4096 tokens

typedef short short8 __attribute__((ext_vector_type(8)));
typedef float floatx4 __attribute__((ext_vector_type(4)));

__device__ __forceinline__ unsigned short f2b(float v) {
    union { float f; unsigned u; } x; x.f = v;
    unsigned r = x.u + 0x7fff + ((x.u >> 16) & 1);   // RNE
    return (unsigned short)(r >> 16);
}

// ---------------- dst = src + bias (row-broadcast); src may alias dst ----------------
__global__ __launch_bounds__(256) void k_bias_add(const float* __restrict__ src,
                                                  const float* __restrict__ bias,
                                                  float* __restrict__ dst) {
    int i = blockIdx.x * 256 + threadIdx.x;
    dst[i] = src[i] + bias[i & (DD - 1)];
}

// ---------------- layernorm (opt. fused embed): x = LN(src)*g + b (bf16) ----------------
// EMB: src = emb + pos (also written to hout for the residual stream); else src = hin.
template <int EMB>
__global__ __launch_bounds__(256) void k_ln(const float* __restrict__ hin,
                                            unsigned short* __restrict__ xout,
                                            const float* __restrict__ g,
                                            const float* __restrict__ b,
                                            const float* __restrict__ emb,
                                            const float* __restrict__ pos,
                                            float* __restrict__ hout) {
    __shared__ float red[4];
    __shared__ float bc1, bc2;
    int t = blockIdx.x;
    int tid = threadIdx.x;
    int lane = tid & 63, wv = tid >> 6;
    float v0, v1;
    if (EMB) {
        const float* erow = emb + (size_t)t * DD;
        const float* prow = pos + (size_t)(t & (NN - 1)) * DD;
        v0 = erow[tid] + prow[tid];
        v1 = erow[tid + 256] + prow[tid + 256];
        hout[(size_t)t * DD + tid] = v0;
        hout[(size_t)t * DD + tid + 256] = v1;
    } else {
        const float* row = hin + (size_t)t * DD;
        v0 = row[tid];
        v1 = row[tid + 256];
    }

    float s = v0 + v1;
#pragma unroll
    for (int o = 32; o; o >>= 1) s += __shfl_down(s, o, 64);
    if (lane == 0) red[wv] = s;
    __syncthreads();
    if (tid == 0) bc1 = (red[0] + red[1] + red[2] + red[3]) * (1.0f / DD);
    __syncthreads();
    float mu = bc1;
    float d0 = v0 - mu, d1 = v1 - mu;
    s = d0 * d0 + d1 * d1;
#pragma unroll
    for (int o = 32; o; o >>= 1) s += __shfl_down(s, o, 64);
    if (lane == 0) red[wv] = s;
    __syncthreads();
    if (tid == 0) bc2 = (red[0] + red[1] + red[2] + red[3]) * (1.0f / DD);
    __syncthreads();
    float rstd = rsqrtf(bc2 + 1e-5f);
    xout[(size_t)t * DD + tid]       = f2b(d0 * rstd * g[tid] + b[tid]);
    xout[(size_t)t * DD + tid + 256] = f2b(d1 * rstd * g[tid + 256] + b[tid + 256]);
}

__device__ __forceinline__ float gelu_new(float v) {
    const float c = 0.7978845608028654f;   // sqrt(2/pi)
    float u = c * (v + 0.044715f * v * v * v);
    return 0.5f * v * (1.0f + tanhf(u));
}

// ---------------- all-weight transpose+convert, both layers, one dispatch ----------------
#define PL 3145728   // per-layer bf16 WT region (elements)
__global__ __launch_bounds__(256) void k_wt_all(const float* __restrict__ c_attn_w,
                                                const float* __restrict__ out_w,
                                                const float* __restrict__ c_fc_w,
                                                const float* __restrict__ c_proj_w,
                                                unsigned short* __restrict__ wbuf) {
    __shared__ unsigned short t[64][72];
    int bx = blockIdx.x;
    int l = bx / 768;
    int r = bx - l * 768;
    const float* W; unsigned short* WT; int K, N;
    if (r < 192)      { W = c_attn_w + (size_t)l * 512 * 1536; WT = wbuf + (size_t)l * PL;           K = 512;  N = 1536; }
    else if (r < 256) { r -= 192; W = out_w  + (size_t)l * 512 * 512;  WT = wbuf + (size_t)l * PL + 786432;  K = 512;  N = 512; }
    else if (r < 512) { r -= 256; W = c_fc_w + (size_t)l * 512 * 2048; WT = wbuf + (size_t)l * PL + 1048576; K = 512;  N = 2048; }
    else              { r -= 512; W = c_proj_w + (size_t)l * 2048 * 512; WT = wbuf + (size_t)l * PL + 2097152; K = 2048; N = 512; }
    int tiles_n = N >> 6;
    int n0 = (r % tiles_n) * 64, k0 = (r / tiles_n) * 64;

    int tid = threadIdx.x;
    int rr = tid >> 2;
    int c0 = (tid & 3) * 16;
    const float* src = W + (size_t)(k0 + rr) * N + n0 + c0;
#pragma unroll
    for (int u = 0; u < 4; u++) {
        float4 v = *(const float4*)&src[u * 4];
        t[c0 + u * 4 + 0][rr] = f2b(v.x);
        t[c0 + u * 4 + 1][rr] = f2b(v.y);
        t[c0 + u * 4 + 2][rr] = f2b(v.z);
        t[c0 + u * 4 + 3][rr] = f2b(v.w);
    }
    __syncthreads();
    unsigned short* dst = WT + (size_t)(n0 + rr) * K + k0 + c0;
#pragma unroll
    for (int u = 0; u < 4; u++)
        *(uint2*)&dst[u * 4] = *(const uint2*)&t[rr][c0 + u * 4];
}

// ---------------- MFMA GEMM: 128x128, reg-prefetch + LDS dbuf, ONE barrier/iter -----------
// C[M x N] (+)= A[M x K](bf16) @ Bt[N x K]^T. 4 waves (2x2), each 4x4 frags of 16x16x32.
// ATOMIC: fp32 atomicAdd epilogue (+bias when z==0 && bias).
template <int ACT, int BF16OUT, int ATOMIC>
__global__ __launch_bounds__(256) void k_mgemm(const unsigned short* __restrict__ Ab,
                                               const unsigned short* __restrict__ Bt,
                                               const float* __restrict__ bias,
                                               float* __restrict__ Cp,
                                               unsigned short* __restrict__ Cb,
                                               int Kfull, int Kchunk, int N) {
    __shared__ unsigned short Als[2][8 * 512];   // frag-contiguous: 8 blocks of 16 rows x 32 k
    __shared__ unsigned short Bls[2][8 * 512];

    int tid = threadIdx.x;
    int l = tid & 63, w = tid >> 6;
    int wm = w >> 1, wn = w & 1;
    int m0 = blockIdx.y * 128, n0 = blockIdx.x * 128;
    int kb = blockIdx.z * Kchunk;
    int lr = l & 15;
    int lk = (l >> 4) * 8;

    const unsigned short* Ap0 = Ab + (size_t)(m0 + (w * 2 + 0) * 16 + lr) * Kfull + kb + lk;
    const unsigned short* Ap1 = Ab + (size_t)(m0 + (w * 2 + 1) * 16 + lr) * Kfull + kb + lk;
    const unsigned short* Bp0 = Bt + (size_t)(n0 + (w * 2 + 0) * 16 + lr) * Kfull + kb + lk;
    const unsigned short* Bp1 = Bt + (size_t)(n0 + (w * 2 + 1) * 16 + lr) * Kfull + kb + lk;
    int la0 = (w * 2 + 0) * 512 + l * 8;
    int la1 = (w * 2 + 1) * 512 + l * 8;

    floatx4 acc[4][4];
#pragma unroll
    for (int i = 0; i < 4; i++)
#pragma unroll
        for (int j = 0; j < 4; j++) acc[i][j] = (floatx4){0.f, 0.f, 0.f, 0.f};

    int nit = Kchunk >> 5;

    // prologue: tile 0 -> buf0; prefetch tile 1 -> regs
    uint4 ra0 = *(const uint4*)Ap0;
    uint4 ra1 = *(const uint4*)Ap1;
    uint4 rb0 = *(const uint4*)Bp0;
    uint4 rb1 = *(const uint4*)Bp1;
    *(uint4*)&Als[0][la0] = ra0;
    *(uint4*)&Als[0][la1] = ra1;
    *(uint4*)&Bls[0][la0] = rb0;
    *(uint4*)&Bls[0][la1] = rb1;
    if (nit > 1) {
        ra0 = *(const uint4*)(Ap0 + 32);
        ra1 = *(const uint4*)(Ap1 + 32);
        rb0 = *(const uint4*)(Bp0 + 32);
        rb1 = *(const uint4*)(Bp1 + 32);
    }
    __syncthreads();

    for (int it = 0; it < nit; it++) {
        int c = it & 1;
        if (it + 1 < nit) {          // regs hold tile it+1 -> other buffer
            *(uint4*)&Als[c ^ 1][la0] = ra0;
            *(uint4*)&Als[c ^ 1][la1] = ra1;
            *(uint4*)&Bls[c ^ 1][la0] = rb0;
            *(uint4*)&Bls[c ^ 1][la1] = rb1;
        }
        if (it + 2 < nit) {          // prefetch tile it+2
            int ko = (it + 2) << 5;
            ra0 = *(const uint4*)(Ap0 + ko);
            ra1 = *(const uint4*)(Ap1 + ko);
            rb0 = *(const uint4*)(Bp0 + ko);
            rb1 = *(const uint4*)(Bp1 + ko);
        }
        short8 a[4], b[4];
#pragma unroll
        for (int i = 0; i < 4; i++) {
            a[i] = *(const short8*)&Als[c][(wm * 4 + i) * 512 + l * 8];
            b[i] = *(const short8*)&Bls[c][(wn * 4 + i) * 512 + l * 8];
        }
#pragma unroll
        for (int i = 0; i < 4; i++)
#pragma unroll
            for (int j = 0; j < 4; j++)
                acc[i][j] = __builtin_amdgcn_mfma_f32_16x16x32_bf16(a[i], b[j], acc[i][j], 0, 0, 0);
        __syncthreads();
    }

    // epilogue: C/D layout col=lane&15, row=(lane>>4)*4+reg
    int col_in = l & 15, rquad = (l >> 4) * 4;
    bool addb = (!ATOMIC) || (bias != nullptr && blockIdx.z == 0);
#pragma unroll
    for (int i = 0; i < 4; i++) {
        int gm_base = m0 + wm * 64 + i * 16 + rquad;
#pragma unroll
        for (int j = 0; j < 4; j++) {
            int gn = n0 + wn * 64 + j * 16 + col_in;
            float bv = addb ? bias[gn] : 0.0f;
#pragma unroll
            for (int r = 0; r < 4; r++) {
                size_t off = (size_t)(gm_base + r) * N + gn;
                if (ATOMIC) {
                    atomicAdd(&Cp[off], acc[i][j][r] + bv);
                } else {
                    float v = acc[i][j][r] + bv;
                    if (ACT) v = gelu_new(v);
                    if (BF16OUT) Cb[off] = f2b(v);
                    else Cp[off] = v;
                }
            }
        }
    }
}

// ---------------- MFMA flash attention (R7-measured-best: 2-barrier single-buffer) --------
// qkv bf16 [T,1536] (q|k|v). Max-free softmax: p = exp(s/8 - 8), exact p=0 on diagonal.
// S^T = K·Q^T (A=K, B=Q): C/D gives lane 4 consecutive keys at fixed query m=lr.
__global__ __launch_bounds__(256) void k_attn_mfma(const unsigned short* __restrict__ qkv,
                                                   unsigned short* __restrict__ xatt) {
    __shared__ unsigned short Ks[64 * 72];    // K tile [key][d]
    __shared__ unsigned short Vt[64 * 72];    // V^T tile [d][key]
    __shared__ unsigned short Pls[64 * 72];   // P tile [m][key]

    int qt = blockIdx.x, hd = blockIdx.y, b = blockIdx.z;
    int tid = threadIdx.x;
    int l = tid & 63, w = tid >> 6;
    int lr = l & 15, quad = l >> 4;

    const size_t base = (size_t)b * NN * 1536;

    // Q frags (B-operand): lane col m=lr, k=d=quad*8+j (+32*ss)
    short8 qf[2];
    {
        const unsigned short* qrow = qkv + base + (size_t)(qt * 64 + w * 16 + lr) * 1536 + hd * 64;
        qf[0] = *(const short8*)&qrow[quad * 8];
        qf[1] = *(const short8*)&qrow[quad * 8 + 32];
    }

    floatx4 O[4];   // O[m=quad*4+reg][d=jd*16+lr]
#pragma unroll
    for (int jd = 0; jd < 4; jd++) O[jd] = (floatx4){0.f, 0.f, 0.f, 0.f};
    float lsum = 0.0f;   // per-lane partial row-sum for query m = w*16+lr

    // staging maps
    int sr = tid >> 2, sc = (tid & 3) * 16;          // K: row sr (key), 16-d chunk sc
    int vk = (tid & 15) * 4, vd = (tid >> 4) * 4;    // V: 4 keys x 4 d per thread
    const unsigned short* Kbase = qkv + base + 512 + hd * 64;
    const unsigned short* Vbase = qkv + base + 1024 + hd * 64;

    uint4 rk0, rk1;
    union { uint2 u; unsigned short s[4]; } rv[4];
    rk0 = *(const uint4*)&Kbase[(size_t)sr * 1536 + sc];
    rk1 = *(const uint4*)&Kbase[(size_t)sr * 1536 + sc + 8];
#pragma unroll
    for (int i = 0; i < 4; i++)
        rv[i].u = *(const uint2*)&Vbase[(size_t)(vk + i) * 1536 + vd];

    for (int kt = 0; kt < 32; kt++) {
        __syncthreads();   // prev iter's Ks/Vt reads done
        *(uint4*)&Ks[sr * 72 + sc]     = rk0;
        *(uint4*)&Ks[sr * 72 + sc + 8] = rk1;
#pragma unroll
        for (int j = 0; j < 4; j++) {
            union { uint2 u; unsigned short s[4]; } pk;
            pk.s[0] = rv[0].s[j]; pk.s[1] = rv[1].s[j];
            pk.s[2] = rv[2].s[j]; pk.s[3] = rv[3].s[j];
            *(uint2*)&Vt[(vd + j) * 72 + vk] = pk.u;
        }
        __syncthreads();
        if (kt < 31) {   // prefetch next K/V tile
            int kn = (kt + 1) * 64;
            rk0 = *(const uint4*)&Kbase[(size_t)(kn + sr) * 1536 + sc];
            rk1 = *(const uint4*)&Kbase[(size_t)(kn + sr) * 1536 + sc + 8];
#pragma unroll
            for (int i = 0; i < 4; i++)
                rv[i].u = *(const uint2*)&Vbase[(size_t)(kn + vk + i) * 1536 + vd];
        }

        // S^T = K Q^T: s[jn] rows key=jn*16+quad*4+reg, col m=lr
        floatx4 s[4];
#pragma unroll
        for (int jn = 0; jn < 4; jn++) s[jn] = (floatx4){0.f, 0.f, 0.f, 0.f};
#pragma unroll
        for (int ss = 0; ss < 2; ss++)
#pragma unroll
            for (int jn = 0; jn < 4; jn++) {
                short8 ak = *(const short8*)&Ks[(jn * 16 + lr) * 72 + ss * 32 + quad * 8];
                s[jn] = __builtin_amdgcn_mfma_f32_16x16x32_bf16(ak, qf[ss], s[jn], 0, 0, 0);
            }

        // p = exp(s/8 - 8); mask diag; accumulate lsum; pack 4 consecutive keys -> b64 write
        int mq = w * 16 + lr;   // query index within 64-row q tile
#pragma unroll
        for (int jn = 0; jn < 4; jn++) {
            union { uint2 u; unsigned short h[4]; } pk;
#pragma unroll
            for (int r = 0; r < 4; r++) {
                float p = __expf(s[jn][r] * 0.125f - 8.0f);
                if (kt == qt && mq == jn * 16 + quad * 4 + r) p = 0.0f;
                lsum += p;
                pk.h[r] = f2b(p);
            }
            *(uint2*)&Pls[mq * 72 + jn * 16 + quad * 4] = pk.u;
        }

        // O += P V   (P rows written/read by the same wave; no barrier needed)
#pragma unroll
        for (int ss = 0; ss < 2; ss++) {
            short8 ap = *(const short8*)&Pls[(w * 16 + lr) * 72 + ss * 32 + quad * 8];
#pragma unroll
            for (int jd = 0; jd < 4; jd++) {
                short8 bv = *(const short8*)&Vt[(jd * 16 + lr) * 72 + ss * 32 + quad * 8];
                O[jd] = __builtin_amdgcn_mfma_f32_16x16x32_bf16(ap, bv, O[jd], 0, 0, 0);
            }
        }
    }

    // reduce lsum across quads (lanes lr, lr+16, lr+32, lr+48 hold same query)
    lsum += __shfl_xor(lsum, 16);
    lsum += __shfl_xor(lsum, 32);
#pragma unroll
    for (int r = 0; r < 4; r++) {
        float inv = 1.0f / __shfl(lsum, quad * 4 + r, 16);
        size_t tok = (size_t)b * NN + qt * 64 + w * 16 + quad * 4 + r;
#pragma unroll
        for (int jd = 0; jd < 4; jd++)
            xatt[tok * DD + hd * 64 + jd * 16 + lr] = f2b(O[jd][r] * inv);
    }
}

extern "C" void kernel_launch(void* const* d_in, const int* in_sizes, int n_in,
                              void* d_out, int out_size, void* d_ws, size_t ws_size,
                              hipStream_t stream) {
    const float* emb      = (const float*)d_in[0];
    const float* pos      = (const float*)d_in[1];
    const float* c_attn_w = (const float*)d_in[2];
    const float* c_attn_b = (const float*)d_in[3];
    const float* out_w    = (const float*)d_in[4];
    const float* out_b    = (const float*)d_in[5];
    const float* ln1_g    = (const float*)d_in[6];
    const float* ln1_b    = (const float*)d_in[7];
    const float* c_fc_w   = (const float*)d_in[8];
    const float* c_fc_b   = (const float*)d_in[9];
    const float* c_proj_w = (const float*)d_in[10];
    const float* c_proj_b = (const float*)d_in[11];
    const float* ln2_g    = (const float*)d_in[12];
    const float* ln2_b    = (const float*)d_in[13];

    // workspace: 8 + 16.8 + 4 + 4 + 12.6 = ~45.4 MB
    char* p = (char*)d_ws;
    float* h = (float*)p;                       p += (size_t)TT * DD * 4;      // fp32 residual
    unsigned short* act = (unsigned short*)p;   p += (size_t)TT * 2048 * 2;    // qkvb/ffa union
    unsigned short* x = (unsigned short*)p;     p += (size_t)TT * DD * 2;      // LN out
    unsigned short* xatt = (unsigned short*)p;  p += (size_t)TT * DD * 2;      // attn out
    unsigned short* wbuf = (unsigned short*)p;                                 // bf16 W^T (both layers)

    unsigned short* qkvb = act;
    unsigned short* ffa  = act;
    float* out = (float*)d_out;

    k_wt_all<<<1536, 256, 0, stream>>>(c_attn_w, out_w, c_fc_w, c_proj_w, wbuf);

    for (int l = 0; l < LL; l++) {
        unsigned short* wqkv_t  = wbuf + (size_t)l * PL;
        unsigned short* wout_t  = wqkv_t + 786432;
        unsigned short* wfc_t   = wqkv_t + 1048576;
        unsigned short* wproj_t = wqkv_t + 2097152;

        // x = LN1(h)  (layer 0: fused embed, also writes h)
        if (l == 0)
            k_ln<1><<<TT, 256, 0, stream>>>(nullptr, x, ln1_g, ln1_b, emb, pos, h);
        else
            k_ln<0><<<TT, 256, 0, stream>>>(h, x, ln1_g + l * DD, ln1_b + l * DD,
                                            nullptr, nullptr, nullptr);
        // qkvb = x @ Wqkv + b  (bf16)
        k_mgemm<0, 1, 0><<<dim3(1536 / 128, TT / 128), 256, 0, stream>>>(
            x, wqkv_t, c_attn_b + l * 1536, nullptr, qkvb, 512, 512, 1536);
        // xatt = attention(qkvb)  (bf16)
        k_attn_mfma<<<dim3(NN / 64, HH, BB), 256, 0, stream>>>(qkvb, xatt);
        // h += xatt @ Wout + out_b  (split-K=2 fp32 atomics; bias folded into z==0)
        k_mgemm<0, 0, 1><<<dim3(512 / 128, TT / 128, 2), 256, 0, stream>>>(
            xatt, wout_t, out_b + l * DD, h, nullptr, 512, 256, 512);
        // x = LN2(h)
        k_ln<0><<<TT, 256, 0, stream>>>(h, x, ln2_g + l * DD, ln2_b + l * DD,
                                        nullptr, nullptr, nullptr);
        // ffa = gelu(x @ Wfc + b)  (bf16; qkvb dead)
        k_mgemm<1, 1, 0><<<dim3(2048 / 128, TT / 128), 256, 0, stream>>>(
            x, wfc_t, c_fc_b + l * 2048, nullptr, ffa, 512, 512, 2048);
        // h/out += ffa @ Wproj + proj_b  (split-K=4 fp32 atomics)
        if (l == LL - 1) {
            k_bias_add<<<TT * DD / 256, 256, 0, stream>>>(h, c_proj_b + l * DD, out);
            k_mgemm<0, 0, 1><<<dim3(512 / 128, TT / 128, 4), 256, 0, stream>>>(
                ffa, wproj_t, nullptr, out, nullptr, 2048, 512, 512);
        } else {
            k_mgemm<0, 0, 1><<<dim3(512 / 128, TT / 128, 4), 256, 0, stream>>>(
                ffa, wproj_t, c_proj_b + l * DD, h, nullptr, 2048, 512, 512);
        }
    }
}